// Round 3
// baseline (472.382 us; speedup 1.0000x reference)
//
#include <hip/hip_runtime.h>
#include <hip/hip_bf16.h>

// Problem constants (fixed by setup_inputs)
#define T_TOK 2048     // B*S tokens
#define D_MODEL 1024
#define F_FF 4096
#define N_EXP 8
#define BM 64          // M tile (also expert-segment padding quantum)
#define MAXMT (T_TOK / BM + N_EXP)   // 40: worst-case number of M tiles
#define LNEPS 1e-5f

typedef __bf16 bf16x8 __attribute__((ext_vector_type(8)));
typedef float f32x4 __attribute__((ext_vector_type(4)));

// ---------------------------------------------------------------------------
// K1: per-token routing + LN stats. One wave (64 lanes) per token.
// ---------------------------------------------------------------------------
__global__ __launch_bounds__(64) void assign_kernel(
    const float* __restrict__ x, const float* __restrict__ cent,
    int* __restrict__ eid, int* __restrict__ rank, float* __restrict__ alpha,
    float* __restrict__ mu, float* __restrict__ rstd, int* __restrict__ cnt)
{
    const int t = blockIdx.x;
    const int lane = threadIdx.x;
    const float* xr = x + (size_t)t * D_MODEL;

    float s = 0.f, sq = 0.f;
    float dot[N_EXP];
#pragma unroll
    for (int e = 0; e < N_EXP; e++) dot[e] = 0.f;

#pragma unroll
    for (int i0 = 0; i0 < D_MODEL; i0 += 256) {
        const int i = i0 + lane * 4;
        float4 v = *(const float4*)&xr[i];
        s  += v.x + v.y + v.z + v.w;
        sq += v.x * v.x + v.y * v.y + v.z * v.z + v.w * v.w;
#pragma unroll
        for (int e = 0; e < N_EXP; e++) {
            float4 c = *(const float4*)&cent[(size_t)e * D_MODEL + i];
            dot[e] += v.x * c.x + v.y * c.y + v.z * c.z + v.w * c.w;
        }
    }
    // wave-64 butterfly reduce (10 values)
#pragma unroll
    for (int off = 32; off > 0; off >>= 1) {
        s  += __shfl_down(s, off);
        sq += __shfl_down(sq, off);
#pragma unroll
        for (int e = 0; e < N_EXP; e++) dot[e] += __shfl_down(dot[e], off);
    }
    if (lane == 0) {
        float m = s * (1.f / D_MODEL);
        float var = sq * (1.f / D_MODEL) - m * m;
        int be = 0; float bv = dot[0];
#pragma unroll
        for (int e = 1; e < N_EXP; e++) { if (dot[e] > bv) { bv = dot[e]; be = e; } }
        eid[t] = be;
        alpha[t] = 1.f / (1.f + __expf(-bv));
        mu[t] = m;
        rstd[t] = rsqrtf(var + LNEPS);
        rank[t] = atomicAdd(&cnt[be], 1);
    }
}

// ---------------------------------------------------------------------------
// K2: build padded segment bases + tile map (single thread; trivial work)
// ---------------------------------------------------------------------------
__global__ void plan_kernel(const int* __restrict__ cnt, int* __restrict__ segBase,
                            int* __restrict__ tileE, int* __restrict__ tileRow,
                            int* __restrict__ numTiles)
{
    if (threadIdx.x == 0 && blockIdx.x == 0) {
        int off = 0, nt = 0;
        for (int e = 0; e < N_EXP; e++) {
            segBase[e] = off;
            int tiles = (cnt[e] + BM - 1) / BM;
            for (int i = 0; i < tiles; i++) { tileE[nt] = e; tileRow[nt] = off + i * BM; nt++; }
            off += tiles * BM;
        }
        *numTiles = nt;
    }
}

// ---------------------------------------------------------------------------
// K3: gather to expert-sorted order, apply LN*gamma+beta, cast bf16.
// One wave per token.
// ---------------------------------------------------------------------------
__global__ __launch_bounds__(64) void scatter_kernel(
    const float* __restrict__ x, const float* __restrict__ gamma, const float* __restrict__ beta,
    const int* __restrict__ eid, const int* __restrict__ rank, const float* __restrict__ alpha,
    const int* __restrict__ segBase, const float* __restrict__ mu, const float* __restrict__ rstd,
    __bf16* __restrict__ Hin, int* __restrict__ tokSorted, float* __restrict__ alphaSorted)
{
    const int t = blockIdx.x;
    const int lane = threadIdx.x;
    const int e = eid[t];
    const int pos = segBase[e] + rank[t];
    if (lane == 0) { tokSorted[pos] = t; alphaSorted[pos] = alpha[t]; }
    const float m = mu[t], r = rstd[t];
    const float* xr = x + (size_t)t * D_MODEL;
    const float* g = gamma + (size_t)e * D_MODEL;
    const float* b = beta + (size_t)e * D_MODEL;
    __bf16* hr = Hin + (size_t)pos * D_MODEL;
#pragma unroll
    for (int i0 = 0; i0 < D_MODEL; i0 += 256) {
        const int i = i0 + lane * 4;
        float4 v = *(const float4*)&xr[i];
        float4 gv = *(const float4*)&g[i];
        float4 bv = *(const float4*)&b[i];
        __bf16 o[4];
        o[0] = (__bf16)((v.x - m) * r * gv.x + bv.x);
        o[1] = (__bf16)((v.y - m) * r * gv.y + bv.y);
        o[2] = (__bf16)((v.z - m) * r * gv.z + bv.z);
        o[3] = (__bf16)((v.w - m) * r * gv.w + bv.w);
        *(uint2*)&hr[i] = *(const uint2*)o;
    }
}

// ---------------------------------------------------------------------------
// Grouped GEMM: A[bf16, row-major, expert-sorted+padded] @ W[e][fp32 KDxND]
// 64x64 tile, BK=64, 4 waves (2x2), mfma_f32_16x16x32_bf16.
// FINAL=false: G = relu(acc + b1) -> bf16
// FINAL=true : out[tok] = x[tok] + alpha*(acc + b2)   (pad rows masked)
// ---------------------------------------------------------------------------
template<int KD, int ND, bool FINAL>
__global__ __launch_bounds__(256) void gemm_kernel(
    const __bf16* __restrict__ A, const float* __restrict__ Wall,
    const float* __restrict__ bias,
    __bf16* __restrict__ Gout,
    float* __restrict__ out, const float* __restrict__ x,
    const int* __restrict__ tokSorted, const float* __restrict__ alphaSorted,
    const int* __restrict__ tileE, const int* __restrict__ tileRow,
    const int* __restrict__ numTiles)
{
    const int mt = blockIdx.y;
    if (mt >= *numTiles) return;
    const int e = tileE[mt];
    const int row0 = tileRow[mt];
    const int n0 = blockIdx.x * 64;
    const float* W = Wall + (size_t)e * KD * ND;
    const int tid = threadIdx.x;

    // +8 bf16 pad per row: row stride 144B -> 2-way max bank aliasing (free)
    __shared__ __align__(16) __bf16 As[64 * 72];
    __shared__ __align__(16) __bf16 Bs[64 * 72];   // stored transposed: [n][k]

    f32x4 acc[2][2] = {};

    const int lane = tid & 63;
    const int wv = tid >> 6;
    const int mbase = (wv >> 1) * 32, nbase = (wv & 1) * 32;
    const int kl = (lane >> 4) * 8, rl = lane & 15;

    const int ar = tid >> 2, ac = (tid & 3) * 8;     // A stage map
    const int bk = tid >> 4, bn = (tid & 15) * 4;    // B stage map

    for (int k0 = 0; k0 < KD; k0 += 64) {
        // stage A (bf16, coalesced 16B)
        const __bf16* asrc = A + (size_t)(row0 + ar) * KD + k0 + ac;
        *(uint4*)&As[ar * 72 + ac]      = *(const uint4*)asrc;
        *(uint4*)&As[ar * 72 + ac + 32] = *(const uint4*)(asrc + 32);
        // stage B: coalesced fp32 load, bf16-convert, transpose into LDS
#pragma unroll
        for (int j = 0; j < 4; j++) {
            int k = bk + j * 16;
            float4 w4 = *(const float4*)&W[(size_t)(k0 + k) * ND + n0 + bn];
            Bs[(bn + 0) * 72 + k] = (__bf16)w4.x;
            Bs[(bn + 1) * 72 + k] = (__bf16)w4.y;
            Bs[(bn + 2) * 72 + k] = (__bf16)w4.z;
            Bs[(bn + 3) * 72 + k] = (__bf16)w4.w;
        }
        __syncthreads();
#pragma unroll
        for (int kk = 0; kk < 64; kk += 32) {
            bf16x8 a0 = *(const bf16x8*)&As[(mbase + rl) * 72 + kk + kl];
            bf16x8 a1 = *(const bf16x8*)&As[(mbase + 16 + rl) * 72 + kk + kl];
            bf16x8 b0 = *(const bf16x8*)&Bs[(nbase + rl) * 72 + kk + kl];
            bf16x8 b1 = *(const bf16x8*)&Bs[(nbase + 16 + rl) * 72 + kk + kl];
            acc[0][0] = __builtin_amdgcn_mfma_f32_16x16x32_bf16(a0, b0, acc[0][0], 0, 0, 0);
            acc[0][1] = __builtin_amdgcn_mfma_f32_16x16x32_bf16(a0, b1, acc[0][1], 0, 0, 0);
            acc[1][0] = __builtin_amdgcn_mfma_f32_16x16x32_bf16(a1, b0, acc[1][0], 0, 0, 0);
            acc[1][1] = __builtin_amdgcn_mfma_f32_16x16x32_bf16(a1, b1, acc[1][1], 0, 0, 0);
        }
        __syncthreads();
    }

    // epilogue. D frag: col = lane&15, row = (lane>>4)*4 + j  [m89-verified]
#pragma unroll
    for (int mi = 0; mi < 2; mi++)
#pragma unroll
        for (int ni = 0; ni < 2; ni++) {
            const int gr0 = row0 + mbase + mi * 16 + (lane >> 4) * 4;
            const int gc = n0 + nbase + ni * 16 + rl;
            const float bv = bias[(size_t)e * ND + gc];
            if constexpr (!FINAL) {
#pragma unroll
                for (int j = 0; j < 4; j++) {
                    float v = acc[mi][ni][j] + bv;
                    Gout[(size_t)(gr0 + j) * ND + gc] = (__bf16)(v > 0.f ? v : 0.f);
                }
            } else {
#pragma unroll
                for (int j = 0; j < 4; j++) {
                    const int gr = gr0 + j;
                    const unsigned tok = (unsigned)tokSorted[gr];
                    if (tok < (unsigned)T_TOK) {   // pad rows: poisoned 0xAAAAAAAA fails this
                        const size_t oi = (size_t)tok * ND + gc;
                        out[oi] = x[oi] + alphaSorted[gr] * (acc[mi][ni][j] + bv);
                    }
                }
            }
        }
}

// ---------------------------------------------------------------------------
extern "C" void kernel_launch(void* const* d_in, const int* in_sizes, int n_in,
                              void* d_out, int out_size, void* d_ws, size_t ws_size,
                              hipStream_t stream)
{
    const float* x    = (const float*)d_in[0];   // [2,1024,1024]
    const float* cent = (const float*)d_in[1];   // [8,1024]
    const float* w1   = (const float*)d_in[2];   // [8,1024,4096]
    const float* b1   = (const float*)d_in[3];   // [8,4096]
    const float* w2   = (const float*)d_in[4];   // [8,4096,1024]
    const float* b2   = (const float*)d_in[5];   // [8,1024]
    const float* gamma= (const float*)d_in[6];   // [8,1024]
    const float* beta = (const float*)d_in[7];   // [8,1024]
    float* out = (float*)d_out;

    char* ws = (char*)d_ws;
    // workspace layout (~26.3 MB total)
    int*   cnt        = (int*)(ws + 0);           // 8
    int*   numTiles   = (int*)(ws + 32);          // 1
    int*   segBase    = (int*)(ws + 64);          // 8
    int*   tileE      = (int*)(ws + 128);         // <=40
    int*   tileRow    = (int*)(ws + 384);         // <=40
    int*   eid        = (int*)(ws + 1024);        // 2048
    int*   rank       = (int*)(ws + 9216);        // 2048
    float* alpha      = (float*)(ws + 17408);     // 2048
    float* mu         = (float*)(ws + 25600);     // 2048
    float* rstd       = (float*)(ws + 33792);     // 2048
    int*   tokSorted  = (int*)(ws + 41984);       // 2560 (padded rows)
    float* alphaSorted= (float*)(ws + 52224);     // 2560
    __bf16* Hin       = (__bf16*)(ws + 65536);    // 2560*1024  (5 MB)
    __bf16* G         = (__bf16*)(ws + 65536 + 2560 * 1024 * 2); // 2560*4096 (20 MB)

    hipMemsetAsync(cnt, 0, 32, stream);

    assign_kernel<<<T_TOK, 64, 0, stream>>>(x, cent, eid, rank, alpha, mu, rstd, cnt);
    plan_kernel<<<1, 64, 0, stream>>>(cnt, segBase, tileE, tileRow, numTiles);
    scatter_kernel<<<T_TOK, 64, 0, stream>>>(x, gamma, beta, eid, rank, alpha,
                                             segBase, mu, rstd, Hin, tokSorted, alphaSorted);
    gemm_kernel<D_MODEL, F_FF, false><<<dim3(F_FF / 64, MAXMT), 256, 0, stream>>>(
        Hin, w1, b1, G, nullptr, nullptr, nullptr, nullptr, tileE, tileRow, numTiles);
    gemm_kernel<F_FF, D_MODEL, true><<<dim3(D_MODEL / 64, MAXMT), 256, 0, stream>>>(
        G, w2, b2, nullptr, out, x, tokSorted, alphaSorted, tileE, tileRow, numTiles);
}

// Round 4
// 431.956 us; speedup vs baseline: 1.0936x; 1.0936x over previous
//
#include <hip/hip_runtime.h>
#include <hip/hip_bf16.h>

// Problem constants (fixed by setup_inputs)
#define T_TOK 2048     // B*S tokens
#define D_MODEL 1024
#define F_FF 4096
#define N_EXP 8
#define BM 128         // M tile (also expert-segment padding quantum)
#define MAXMT (T_TOK / BM + N_EXP)   // 24: worst-case number of M tiles
#define MROWS 3072     // padded-row buffer capacity (2048 + 8*127 -> 3072)
#define LNEPS 1e-5f
#define WSTRIDE 4194304  // per-expert weight elems (1024*4096)

typedef __bf16 bf16x8 __attribute__((ext_vector_type(8)));
typedef float f32x4 __attribute__((ext_vector_type(4)));

// async global->LDS, 16B per lane. LDS dest = uniform base + lane*16.
__device__ __forceinline__ void gload16(const void* g, void* l) {
    __builtin_amdgcn_global_load_lds(
        (const __attribute__((address_space(1))) unsigned int*)g,
        (__attribute__((address_space(3))) unsigned int*)l, 16, 0, 0);
}

// ---------------------------------------------------------------------------
// K1: per-token routing + LN stats. One wave per token.
// ---------------------------------------------------------------------------
__global__ __launch_bounds__(64) void assign_kernel(
    const float* __restrict__ x, const float* __restrict__ cent,
    int* __restrict__ eid, int* __restrict__ rank, float* __restrict__ alpha,
    float* __restrict__ mu, float* __restrict__ rstd, int* __restrict__ cnt)
{
    const int t = blockIdx.x;
    const int lane = threadIdx.x;
    const float* xr = x + (size_t)t * D_MODEL;

    float s = 0.f, sq = 0.f;
    float dot[N_EXP];
#pragma unroll
    for (int e = 0; e < N_EXP; e++) dot[e] = 0.f;

#pragma unroll
    for (int i0 = 0; i0 < D_MODEL; i0 += 256) {
        const int i = i0 + lane * 4;
        float4 v = *(const float4*)&xr[i];
        s  += v.x + v.y + v.z + v.w;
        sq += v.x * v.x + v.y * v.y + v.z * v.z + v.w * v.w;
#pragma unroll
        for (int e = 0; e < N_EXP; e++) {
            float4 c = *(const float4*)&cent[(size_t)e * D_MODEL + i];
            dot[e] += v.x * c.x + v.y * c.y + v.z * c.z + v.w * c.w;
        }
    }
#pragma unroll
    for (int off = 32; off > 0; off >>= 1) {
        s  += __shfl_down(s, off);
        sq += __shfl_down(sq, off);
#pragma unroll
        for (int e = 0; e < N_EXP; e++) dot[e] += __shfl_down(dot[e], off);
    }
    if (lane == 0) {
        float m = s * (1.f / D_MODEL);
        float var = sq * (1.f / D_MODEL) - m * m;
        int be = 0; float bv = dot[0];
#pragma unroll
        for (int e = 1; e < N_EXP; e++) { if (dot[e] > bv) { bv = dot[e]; be = e; } }
        eid[t] = be;
        alpha[t] = 1.f / (1.f + __expf(-bv));
        mu[t] = m;
        rstd[t] = rsqrtf(var + LNEPS);
        rank[t] = atomicAdd(&cnt[be], 1);
    }
}

// ---------------------------------------------------------------------------
// K2: padded segment bases + tile map (quantum 128)
// ---------------------------------------------------------------------------
__global__ void plan_kernel(const int* __restrict__ cnt, int* __restrict__ segBase,
                            int* __restrict__ tileE, int* __restrict__ tileRow,
                            int* __restrict__ numTiles)
{
    if (threadIdx.x == 0 && blockIdx.x == 0) {
        int off = 0, nt = 0;
        for (int e = 0; e < N_EXP; e++) {
            segBase[e] = off;
            int tiles = (cnt[e] + BM - 1) / BM;
            for (int i = 0; i < tiles; i++) { tileE[nt] = e; tileRow[nt] = off + i * BM; nt++; }
            off += tiles * BM;
        }
        *numTiles = nt;
    }
}

// ---------------------------------------------------------------------------
// K3: gather to expert-sorted order, LN*gamma+beta, cast bf16.
// ---------------------------------------------------------------------------
__global__ __launch_bounds__(64) void scatter_kernel(
    const float* __restrict__ x, const float* __restrict__ gamma, const float* __restrict__ beta,
    const int* __restrict__ eid, const int* __restrict__ rank, const float* __restrict__ alpha,
    const int* __restrict__ segBase, const float* __restrict__ mu, const float* __restrict__ rstd,
    __bf16* __restrict__ Hin, int* __restrict__ tokSorted, float* __restrict__ alphaSorted)
{
    const int t = blockIdx.x;
    const int lane = threadIdx.x;
    const int e = eid[t];
    const int pos = segBase[e] + rank[t];
    if (lane == 0) { tokSorted[pos] = t; alphaSorted[pos] = alpha[t]; }
    const float m = mu[t], r = rstd[t];
    const float* xr = x + (size_t)t * D_MODEL;
    const float* g = gamma + (size_t)e * D_MODEL;
    const float* b = beta + (size_t)e * D_MODEL;
    __bf16* hr = Hin + (size_t)pos * D_MODEL;
#pragma unroll
    for (int i0 = 0; i0 < D_MODEL; i0 += 256) {
        const int i = i0 + lane * 4;
        float4 v = *(const float4*)&xr[i];
        float4 gv = *(const float4*)&g[i];
        float4 bv = *(const float4*)&b[i];
        __bf16 o[4];
        o[0] = (__bf16)((v.x - m) * r * gv.x + bv.x);
        o[1] = (__bf16)((v.y - m) * r * gv.y + bv.y);
        o[2] = (__bf16)((v.z - m) * r * gv.z + bv.z);
        o[3] = (__bf16)((v.w - m) * r * gv.w + bv.w);
        *(uint2*)&hr[i] = *(const uint2*)o;
    }
}

// ---------------------------------------------------------------------------
// K4: weight transpose+convert: fp32 [K][N] -> bf16 [N][K], per expert.
// 64x64 tiles via LDS (pad 67 fp32 -> 2-way max bank aliasing, free).
// ---------------------------------------------------------------------------
template<int K, int N>
__global__ __launch_bounds__(256) void wtrans_kernel(
    const float* __restrict__ W, __bf16* __restrict__ Wt)
{
    constexpr int TPE = (K / 64) * (N / 64);   // 1024
    const int b = blockIdx.x;
    const int e = b / TPE;
    const int t = b % TPE;
    const int kt = t / (N / 64);
    const int nt = t % (N / 64);
    const float* in = W + (size_t)e * K * N + (size_t)kt * 64 * N + nt * 64;
    __bf16* outp = Wt + (size_t)e * K * N + (size_t)nt * 64 * K + kt * 64;
    __shared__ float lds[64 * 67];
    const int tid = threadIdx.x;
#pragma unroll
    for (int i = 0; i < 4; ++i) {
        int idx = tid + i * 256;            // 0..1023
        int r = idx >> 4, c4 = (idx & 15) * 4;
        float4 v = *(const float4*)&in[(size_t)r * N + c4];
        lds[r * 67 + c4 + 0] = v.x;
        lds[r * 67 + c4 + 1] = v.y;
        lds[r * 67 + c4 + 2] = v.z;
        lds[r * 67 + c4 + 3] = v.w;
    }
    __syncthreads();
#pragma unroll
    for (int i = 0; i < 2; ++i) {
        int idx = tid + i * 256;            // 0..511
        int orow = idx >> 3, g = idx & 7;
        __bf16 o[8];
#pragma unroll
        for (int j = 0; j < 8; ++j)
            o[j] = (__bf16)lds[(g * 8 + j) * 67 + orow];
        *(uint4*)&outp[(size_t)orow * K + g * 8] = *(const uint4*)o;
    }
}

// ---------------------------------------------------------------------------
// K5/K6: grouped GEMM, m97 structure. 128x128 tile, BK=64, 4 waves, 4x4 accs.
// A [M][LDA] bf16 row-major; B = Wt [N][LDB] bf16 row-major (pre-transposed).
// Staging: global_load_lds 16B, XOR-swizzled SOURCE (granule ^= row&7),
// linear LDS dest; ds_read_b128 applies the same XOR -> conflict-free.
// FINAL=false: Out = relu(acc + b1) bf16 [*][4096]
// FINAL=true : P-slice partial bf16 [z][MROWS][1024], no bias.
// ---------------------------------------------------------------------------
template<int LDA, int LDB, int LDOUT, bool FINAL>
__global__ __launch_bounds__(256) void gemm_kernel(
    const __bf16* __restrict__ A, const __bf16* __restrict__ Wt,
    const float* __restrict__ bias, __bf16* __restrict__ Out,
    const int* __restrict__ tileE, const int* __restrict__ tileRow,
    const int* __restrict__ numTiles)
{
    const int mt = blockIdx.y;
    if (mt >= *numTiles) return;
    const int e = tileE[mt];
    const int row0 = tileRow[mt];
    const int n0 = blockIdx.x * 128;
    const int z = blockIdx.z;
    const int k0base = z * 1024;

    const int tid = threadIdx.x;
    const int l = tid & 63, wv = tid >> 6;
    const int wr = wv >> 1, wc = wv & 1;
    const int rl = l & 15, kh = l >> 4;

    __shared__ __align__(16) __bf16 As[128 * 64];
    __shared__ __align__(16) __bf16 Bs[128 * 64];

    const __bf16* Ab = A + (size_t)row0 * LDA;
    const __bf16* Bb = Wt + (size_t)e * WSTRIDE + (size_t)n0 * LDB;

    f32x4 acc[4][4] = {};

    for (int it = 0; it < 16; ++it) {
        const int k0 = k0base + it * 64;
        // stage both tiles: wave wv covers chunks wv*4..wv*4+3 of each (1 KB ea)
#pragma unroll
        for (int c = 0; c < 4; ++c) {
            const int chunk = wv * 4 + c;
            const int g = chunk * 64 + l;          // granule 0..1023
            const int row = g >> 3;
            const int cs = (g & 7) ^ (row & 7);    // pre-swizzled source granule
            gload16(Ab + (size_t)row * LDA + k0 + cs * 8, (char*)As + chunk * 1024);
            gload16(Bb + (size_t)row * LDB + k0 + cs * 8, (char*)Bs + chunk * 1024);
        }
        __syncthreads();   // drains vmcnt -> tiles complete
#pragma unroll
        for (int kk = 0; kk < 64; kk += 32) {
            bf16x8 a[4], b[4];
            const int kg = (kk >> 3) + kh;         // logical k granule
#pragma unroll
            for (int i = 0; i < 4; ++i) {
                const int ar = wr * 64 + i * 16 + rl;
                a[i] = *(const bf16x8*)((const char*)As + ar * 128 + ((kg ^ (ar & 7)) * 16));
                const int br = wc * 64 + i * 16 + rl;
                b[i] = *(const bf16x8*)((const char*)Bs + br * 128 + ((kg ^ (br & 7)) * 16));
            }
#pragma unroll
            for (int mi = 0; mi < 4; ++mi)
#pragma unroll
                for (int ni = 0; ni < 4; ++ni)
                    acc[mi][ni] = __builtin_amdgcn_mfma_f32_16x16x32_bf16(a[mi], b[ni], acc[mi][ni], 0, 0, 0);
        }
        __syncthreads();
    }

    // epilogue. D frag: col = lane&15, row = (lane>>4)*4 + j
#pragma unroll
    for (int mi = 0; mi < 4; ++mi)
#pragma unroll
        for (int ni = 0; ni < 4; ++ni) {
            const int gr0 = row0 + wr * 64 + mi * 16 + kh * 4;
            const int gc = n0 + wc * 64 + ni * 16 + rl;
            if constexpr (!FINAL) {
                const float bv = bias[(size_t)e * F_FF + gc];
#pragma unroll
                for (int j = 0; j < 4; ++j) {
                    float v = acc[mi][ni][j] + bv;
                    Out[(size_t)(gr0 + j) * LDOUT + gc] = (__bf16)(v > 0.f ? v : 0.f);
                }
            } else {
                __bf16* outp = Out + (size_t)z * MROWS * D_MODEL;
#pragma unroll
                for (int j = 0; j < 4; ++j)
                    outp[(size_t)(gr0 + j) * LDOUT + gc] = (__bf16)acc[mi][ni][j];
            }
        }
}

// ---------------------------------------------------------------------------
// K7: split-K reduce + bias + gate + residual, scatter to token order.
// One block per padded row.
// ---------------------------------------------------------------------------
__global__ __launch_bounds__(256) void reduce_kernel(
    const __bf16* __restrict__ P, const float* __restrict__ x,
    const float* __restrict__ b2, const int* __restrict__ tokSorted,
    const float* __restrict__ alphaSorted, const int* __restrict__ eid,
    float* __restrict__ out)
{
    const int r = blockIdx.x;
    const unsigned tok = (unsigned)tokSorted[r];
    if (tok >= (unsigned)T_TOK) return;   // pad rows: poisoned 0xAAAAAAAA
    const int e = eid[tok];
    const float a = alphaSorted[r];
    const int c = threadIdx.x * 4;
    float s0 = 0.f, s1 = 0.f, s2 = 0.f, s3 = 0.f;
#pragma unroll
    for (int zz = 0; zz < 4; ++zz) {
        const __bf16* p = P + ((size_t)zz * MROWS + r) * D_MODEL + c;
        ushort4 v = *(const ushort4*)p;
        s0 += __uint_as_float((unsigned)v.x << 16);
        s1 += __uint_as_float((unsigned)v.y << 16);
        s2 += __uint_as_float((unsigned)v.z << 16);
        s3 += __uint_as_float((unsigned)v.w << 16);
    }
    float4 b = *(const float4*)&b2[(size_t)e * D_MODEL + c];
    float4 xv = *(const float4*)&x[(size_t)tok * D_MODEL + c];
    float4 o;
    o.x = xv.x + a * (s0 + b.x);
    o.y = xv.y + a * (s1 + b.y);
    o.z = xv.z + a * (s2 + b.z);
    o.w = xv.w + a * (s3 + b.w);
    *(float4*)&out[(size_t)tok * D_MODEL + c] = o;
}

// ---------------------------------------------------------------------------
extern "C" void kernel_launch(void* const* d_in, const int* in_sizes, int n_in,
                              void* d_out, int out_size, void* d_ws, size_t ws_size,
                              hipStream_t stream)
{
    const float* x    = (const float*)d_in[0];
    const float* cent = (const float*)d_in[1];
    const float* w1   = (const float*)d_in[2];   // [8,1024,4096]
    const float* b1   = (const float*)d_in[3];
    const float* w2   = (const float*)d_in[4];   // [8,4096,1024]
    const float* b2   = (const float*)d_in[5];
    const float* gamma= (const float*)d_in[6];
    const float* beta = (const float*)d_in[7];
    float* out = (float*)d_out;

    char* ws = (char*)d_ws;
    // workspace layout (~124 MB)
    int*   cnt        = (int*)(ws + 0);
    int*   numTiles   = (int*)(ws + 64);
    int*   segBase    = (int*)(ws + 128);
    int*   tileE      = (int*)(ws + 256);         // 32 ints
    int*   tileRow    = (int*)(ws + 512);         // 32 ints
    int*   eid        = (int*)(ws + 1024);        // 2048
    int*   rank       = (int*)(ws + 9216);
    float* alpha      = (float*)(ws + 17408);
    float* mu         = (float*)(ws + 25600);
    float* rstd       = (float*)(ws + 33792);
    int*   tokSorted  = (int*)(ws + 41984);       // 3072
    float* alphaSorted= (float*)(ws + 54272);     // 3072
    __bf16* Hin = (__bf16*)(ws + 131072);                      // [3072][1024]  6 MB
    __bf16* G   = (__bf16*)(ws + 131072 + (size_t)MROWS*D_MODEL*2);          // [3072][4096] 24 MB
    __bf16* Wt  = (__bf16*)(ws + 131072 + (size_t)MROWS*(D_MODEL+F_FF)*2);   // [8][N][K]    64 MB (shared W1t/W2t)
    __bf16* P   = (__bf16*)(ws + 131072 + (size_t)MROWS*(D_MODEL+F_FF)*2
                                        + (size_t)N_EXP*WSTRIDE*2);          // [4][3072][1024] 24 MB

    hipMemsetAsync(cnt, 0, 64, stream);

    assign_kernel<<<T_TOK, 64, 0, stream>>>(x, cent, eid, rank, alpha, mu, rstd, cnt);
    plan_kernel<<<1, 64, 0, stream>>>(cnt, segBase, tileE, tileRow, numTiles);
    // W1 [1024][4096] -> Wt [4096][1024] per expert
    wtrans_kernel<D_MODEL, F_FF><<<8192, 256, 0, stream>>>(w1, Wt);
    scatter_kernel<<<T_TOK, 64, 0, stream>>>(x, gamma, beta, eid, rank, alpha,
                                             segBase, mu, rstd, Hin, tokSorted, alphaSorted);
    // G = relu(Hin @ W1 + b1)
    gemm_kernel<D_MODEL, D_MODEL, F_FF, false><<<dim3(F_FF / 128, MAXMT, 1), 256, 0, stream>>>(
        Hin, Wt, b1, G, tileE, tileRow, numTiles);
    // W2 [4096][1024] -> Wt [1024][4096] per expert (reuses Wt; gemm1 done, stream-ordered)
    wtrans_kernel<F_FF, D_MODEL><<<8192, 256, 0, stream>>>(w2, Wt);
    // P[z] = partial (G @ W2), split-K=4
    gemm_kernel<F_FF, F_FF, D_MODEL, true><<<dim3(D_MODEL / 128, MAXMT, 4), 256, 0, stream>>>(
        G, Wt, nullptr, P, tileE, tileRow, numTiles);
    // out = x + alpha * (sum_z P + b2), scattered to token order
    reduce_kernel<<<MROWS, 256, 0, stream>>>(P, x, b2, tokSorted, alphaSorted, eid, out);
}